// Round 16
// baseline (1097.797 us; speedup 1.0000x reference)
//
#include <hip/hip_runtime.h>
#include <math.h>

#define NB 16      // batch
#define CIN 3
#define LL 2048
#define DD 256
#define KK 8
#define NDEPTH 4
#define FF 1025
#define FFP 1032   // padded F stride for half2 Xf (u32 units)
#define FFS 1032   // padded F stride for f32 Sf (float2 units), line-aligned rows
#define LOGL 11

typedef _Float16 half8 __attribute__((ext_vector_type(8)));
typedef _Float16 half2v __attribute__((ext_vector_type(2)));
typedef float f32x4 __attribute__((ext_vector_type(4)));

union H8 { half8 h8; unsigned int u[4]; uint4 q; };
union H2 { _Float16 h[2]; unsigned int u; half2v v; };
union PK2 { float2 f2[2]; uint4 q; };

#if defined(__has_builtin)
#if __has_builtin(__builtin_amdgcn_fdot2)
#define HAS_FDOT2 1
#endif
#endif

__device__ inline float fdot2_acc(unsigned int a, unsigned int b, float c){
    H2 ua, ub; ua.u = a; ub.u = b;
#ifdef HAS_FDOT2
    return __builtin_amdgcn_fdot2(ua.v, ub.v, c, false);
#else
    return c + (float)ua.h[0]*(float)ub.h[0] + (float)ua.h[1]*(float)ub.h[1];
#endif
}

__device__ inline float2 cmul(const float2 a, const float2 b){
    return make_float2(a.x*b.x - a.y*b.y, a.x*b.y + a.y*b.x);
}
__device__ inline float2 cadd(const float2 a, const float2 b){ return make_float2(a.x+b.x, a.y+b.y); }
__device__ inline float2 csub(const float2 a, const float2 b){ return make_float2(a.x-b.x, a.y-b.y); }

// radix-8 triple (stages s, s+1, s+2), one 8-group per thread (g in [0,256))
template<bool CONJ>
__device__ inline void r8_stage(float2* a, const float2* __restrict__ tw, int g, int s){
    const int hs = 1 << s;
    int pos = g & (hs-1);
    int grp = g >> s;
    int q = (grp << (s+3)) + pos;
    float2 ws = tw[pos << (LOGL-1-s)];
    float2 w1 = tw[pos << (LOGL-2-s)];
    float2 w2 = tw[(pos+hs) << (LOGL-2-s)];
    float2 v0 = tw[pos << (LOGL-3-s)];
    float2 v1 = tw[(pos+hs) << (LOGL-3-s)];
    float2 v2 = tw[(pos+2*hs) << (LOGL-3-s)];
    float2 v3 = tw[(pos+3*hs) << (LOGL-3-s)];
    if (CONJ){ ws.y=-ws.y; w1.y=-w1.y; w2.y=-w2.y; v0.y=-v0.y; v1.y=-v1.y; v2.y=-v2.y; v3.y=-v3.y; }
    float2 A0=a[q],      A1=a[q+hs],   A2=a[q+2*hs], A3=a[q+3*hs],
           A4=a[q+4*hs], A5=a[q+5*hs], A6=a[q+6*hs], A7=a[q+7*hs];
    float2 t;
    t=cmul(ws,A1); float2 b0=cadd(A0,t), b1=csub(A0,t);
    t=cmul(ws,A3); float2 b2=cadd(A2,t), b3=csub(A2,t);
    t=cmul(ws,A5); float2 b4=cadd(A4,t), b5=csub(A4,t);
    t=cmul(ws,A7); float2 b6=cadd(A6,t), b7=csub(A6,t);
    t=cmul(w1,b2); float2 c0=cadd(b0,t), c2=csub(b0,t);
    t=cmul(w2,b3); float2 c1=cadd(b1,t), c3=csub(b1,t);
    t=cmul(w1,b6); float2 c4=cadd(b4,t), c6=csub(b4,t);
    t=cmul(w2,b7); float2 c5=cadd(b5,t), c7=csub(b5,t);
    t=cmul(v0,c4); a[q]      =cadd(c0,t); a[q+4*hs]=csub(c0,t);
    t=cmul(v1,c5); a[q+hs]   =cadd(c1,t); a[q+5*hs]=csub(c1,t);
    t=cmul(v2,c6); a[q+2*hs] =cadd(c2,t); a[q+6*hs]=csub(c2,t);
    t=cmul(v3,c7); a[q+3*hs] =cadd(c3,t); a[q+7*hs]=csub(c3,t);
}

// final radix-4 pair (stages 9,10), one 4-group per call (g in [0,512))
template<bool CONJ>
__device__ inline void r4_final(float2* a, const float2* __restrict__ tw, int g){
    int pos = g;
    float2 ws = tw[pos << 1];
    float2 w1 = tw[pos];
    float2 w2 = tw[pos + 512];
    if (CONJ){ ws.y=-ws.y; w1.y=-w1.y; w2.y=-w2.y; }
    float2 a0 = a[pos], a1 = a[pos+512], a2 = a[pos+1024], a3 = a[pos+1536];
    float2 t1 = cmul(ws, a1), t3 = cmul(ws, a3);
    float2 x0 = cadd(a0,t1), x1 = csub(a0,t1);
    float2 x2 = cadd(a2,t3), x3 = csub(a2,t3);
    float2 u1 = cmul(w1, x2), u2 = cmul(w2, x3);
    a[pos]      = cadd(x0,u1);
    a[pos+1024] = csub(x0,u1);
    a[pos+512]  = cadd(x1,u2);
    a[pos+1536] = csub(x1,u2);
}

// ---------------- twiddle table ----------------------------------------------------
__global__ void twiddle_kernel(float2* __restrict__ tw){
    int j = blockIdx.x*blockDim.x + threadIdx.x;
    if (j < LL/2){
        double ang = -2.0*3.14159265358979323846*(double)j/(double)LL;
        tw[j] = make_float2((float)cos(ang), (float)sin(ang));
    }
}

// ---------------- convert GLU weights to f16 A-fragment layout ----------------------
__global__ void conv_w_kernel(const float* __restrict__ wv, const float* __restrict__ wg,
                              _Float16* __restrict__ Wf){
    int idx = blockIdx.x*256 + threadIdx.x;   // NDEPTH*2*DD*DD
    int layer = idx >> 17;
    int vg = (idx >> 16) & 1;
    int rem = idx & 65535;
    int o = rem >> 8, d = rem & 255;
    const float* src = (vg ? wg : wv) + ((size_t)layer << 16);
    float val = src[(o << 8) + d];
    size_t dst = ((((size_t)(layer*2+vg)*16 + (o>>4))*8 + (d>>5))*64
                  + (o&15) + 16*((d>>3)&3))*8 + (d&7);
    Wf[dst] = (_Float16)val;
}

// ---------------- theta -> f16 l-pair-packed, transposed: [layer][lp][d][h] half2 ---
__global__ void transpose_theta16_kernel(const float* __restrict__ in,
                                         unsigned int* __restrict__ out){
    __shared__ float tile[2][32][33];
    int m = blockIdx.z;                  // layer*4 + lp
    int layer = m >> 2, lp = m & 3;
    int d0 = blockIdx.x*32, h0 = blockIdx.y*32;
    int tx = threadIdx.x & 31, ty = threadIdx.x >> 5;   // 32 x 8
    const float* src0 = in + ((size_t)layer*KK + 2*lp)*DD*DD;
    const float* src1 = src0 + (size_t)DD*DD;
    #pragma unroll
    for (int i = 0; i < 4; ++i){
        tile[0][ty + i*8][tx] = src0[(size_t)(h0 + ty + i*8)*DD + d0 + tx];
        tile[1][ty + i*8][tx] = src1[(size_t)(h0 + ty + i*8)*DD + d0 + tx];
    }
    __syncthreads();
    #pragma unroll
    for (int i = 0; i < 4; ++i){
        H2 p;
        p.h[0] = (_Float16)tile[0][tx][ty + i*8];
        p.h[1] = (_Float16)tile[1][tx][ty + i*8];
        out[((size_t)m*DD + d0 + ty + i*8)*DD + h0 + tx] = p.u;
    }
}

// ---------------- lift + LayerNorm(layer 0): h f32, z f16 ---------------------------
__global__ __launch_bounds__(256) void lift_ln_kernel(const float* __restrict__ x,
        const float* __restrict__ lw, const float* __restrict__ lb,
        const float* __restrict__ gamma, const float* __restrict__ beta,
        float* __restrict__ h, _Float16* __restrict__ z){
    __shared__ float red[2][4][64];
    __shared__ float stat[2][64];
    __shared__ float gb[512];
    int tid = threadIdx.x;
    int t = tid & 63, dg = tid >> 6;
    int b = blockIdx.y;
    int tg = blockIdx.x*64 + t;
    gb[tid] = gamma[tid];
    gb[256 + tid] = beta[tid];
    const float* xb = x + (size_t)b*CIN*LL;
    float x0 = xb[tg], x1 = xb[LL + tg], x2 = xb[2*LL + tg];
    float coord = (float)tg * (1.0f/(LL-1));
    float hv[64];
    float s = 0.f, ss = 0.f;
    float* hp = h + (size_t)b*DD*LL + tg;
    #pragma unroll
    for (int j = 0; j < 64; ++j){
        int d = dg*64 + j;
        float4 w = *(const float4*)&lw[d*4];
        float v = lb[d];
        v = fmaf(w.x, x0, v); v = fmaf(w.y, x1, v);
        v = fmaf(w.z, x2, v); v = fmaf(w.w, coord, v);
        hv[j] = v;
        s += v; ss = fmaf(v, v, ss);
        hp[(size_t)d*LL] = v;
    }
    red[0][dg][t] = s; red[1][dg][t] = ss;
    __syncthreads();
    if (tid < 64){
        float S1 = red[0][0][tid] + red[0][1][tid] + red[0][2][tid] + red[0][3][tid];
        float S2 = red[1][0][tid] + red[1][1][tid] + red[1][2][tid] + red[1][3][tid];
        float mu = S1*(1.0f/DD);
        float var = S2*(1.0f/DD) - mu*mu;
        stat[0][tid] = mu;
        stat[1][tid] = rsqrtf(var + 1e-5f);
    }
    __syncthreads();
    float mu = stat[0][t], rs = stat[1][t];
    _Float16* zp = z + (size_t)b*DD*LL + tg;
    #pragma unroll
    for (int j = 0; j < 64; ++j){
        int d = dg*64 + j;
        zp[(size_t)d*LL] = (_Float16)((hv[j] - mu)*rs*gb[d] + gb[256 + d]);
    }
}

// ---------------- forward FFT (radix-8), reads f16 z, 2 real channels packed --------
__global__ __launch_bounds__(256) void fft_fwd_pair_kernel(const unsigned int* __restrict__ zh,
                                                           unsigned int* __restrict__ XfH,
                                                           const float2* __restrict__ tw){
    __shared__ float2 a[LL];
    int blk = blockIdx.x;
    const unsigned int* s0 = zh + (size_t)(blk*2)*(LL/2);
    const unsigned int* s1 = s0 + (LL/2);
    int tid = threadIdx.x;
    #pragma unroll
    for (int i = 0; i < 4; ++i){
        int tp = tid + i*256;           // t-pair index 0..1023
        H2 u0, u1;
        u0.u = s0[tp];
        u1.u = s1[tp];
        int t0 = 2*tp, t1 = 2*tp + 1;
        int r0 = __brev((unsigned)t0) >> (32-LOGL);
        int r1 = __brev((unsigned)t1) >> (32-LOGL);
        a[r0] = make_float2((float)u0.h[0], (float)u1.h[0]);
        a[r1] = make_float2((float)u0.h[1], (float)u1.h[1]);
    }
    __syncthreads();
    r8_stage<false>(a, tw, tid, 0);  __syncthreads();
    r8_stage<false>(a, tw, tid, 3);  __syncthreads();
    r8_stage<false>(a, tw, tid, 6);  __syncthreads();
    r4_final<false>(a, tw, tid);
    r4_final<false>(a, tw, tid + 256);
    __syncthreads();
    unsigned int* dst0 = XfH + (size_t)(blk*2)*FFP;
    unsigned int* dst1 = dst0 + FFP;
    #pragma unroll
    for (int i = 0; i < 5; ++i){
        int f = tid + i*256;
        if (f <= 1024){
            int m = (LL - f) & (LL-1);
            float2 A = a[f], B = a[m];
            H2 p0, p1;
            p0.h[0] = (_Float16)(0.5f*(A.x + B.x));
            p0.h[1] = (_Float16)(0.5f*(A.y - B.y));
            p1.h[0] = (_Float16)(0.5f*(A.y + B.y));
            p1.h[1] = (_Float16)(0.5f*(B.x - A.x));
            dst0[f] = p0.u;
            dst1[f] = p1.u;
        }
    }
    if (tid < 7){
        dst0[1025 + tid] = 0u;
        dst1[1025 + tid] = 0u;
    }
}

// ---------------- inverse FFT (radix-8), reads f32 Sf, writes Sfrag -----------------
__global__ __launch_bounds__(256) void fft_inv_pair_kernel(const float2* __restrict__ Sf0,
                                                           unsigned int* __restrict__ Sfrag,
                                                           const float2* __restrict__ tw){
    __shared__ float2 a[LL];
    int blk = blockIdx.x;
    const float2* src0 = Sf0 + (size_t)(blk*2)*FFS;
    const float2* src1 = src0 + FFS;
    int tid = threadIdx.x;
    #pragma unroll
    for (int i = 0; i < LL/256; ++i){
        int idx = tid + i*256;
        float2 Y;
        if (idx <= 1024){
            float2 s0 = src0[idx], s1 = src1[idx];
            Y = make_float2(s0.x - s1.y, s0.y + s1.x);
        } else {
            int m = LL - idx;
            float2 s0 = src0[m], s1 = src1[m];
            Y = make_float2(s0.x + s1.y, s1.x - s0.y);
        }
        int rev = __brev((unsigned)idx) >> (32-LOGL);
        a[rev] = Y;
    }
    __syncthreads();
    r8_stage<true>(a, tw, tid, 0);  __syncthreads();
    r8_stage<true>(a, tw, tid, 3);  __syncthreads();
    r8_stage<true>(a, tw, tid, 6);  __syncthreads();
    r4_final<true>(a, tw, tid);
    r4_final<true>(a, tw, tid + 256);
    __syncthreads();
    int b = blk >> 7, dl = (blk & 127)*2;
    int kc = dl >> 5, lq4 = (dl >> 3) & 3, jh = (dl & 7) >> 1;
    unsigned int* dst = Sfrag + ((size_t)(b*8 + kc)*128)*64*4;
    const float sc = 1.0f/(float)LL;
    #pragma unroll
    for (int i = 0; i < LL/256; ++i){
        int t = tid + i*256;
        float2 v = a[t];
        H2 p;
        p.h[0] = (_Float16)(v.x*sc);
        p.h[1] = (_Float16)(v.y*sc);
        dst[(((t>>4)*64) + (t&15) + 16*lq4)*4 + jh] = p.u;
    }
}

// ---------------- spectral v12: f-tile 4, grid (256,4) -> 4 blocks/CU ---------------
// 8 waves = (hc 0-3) x (ffhalf 0-1); per wave 2 ff x 16 h; dbuf staging, 1 barrier/kc.
__global__ __launch_bounds__(512, 8) void spectral12_kernel(
    const unsigned int* __restrict__ XfH,   // [b][d][FFP] half2 (re,im)
    const unsigned int* __restrict__ th16,  // [4][d][h] this layer, l-pair half2
    const float* __restrict__ phr, const float* __restrict__ phim,
    float2* __restrict__ Sf0){
    __shared__ unsigned int Apairs[2][2048];  // 2 x 8 KB, swizzled fragment layout
    __shared__ unsigned int phi2[2][4][4];    // [pr/pi][ff][lp] f16 l-pairs
    int tid = threadIdx.x;
    int w = tid >> 6, lane = tid & 63;
    int hc = w & 3, fh = w >> 2;
    int n = lane & 15, kp = lane >> 4;
    int f0 = blockIdx.x * 4;
    int h0 = blockIdx.y * 64;
    int h = h0 + hc*16 + n;

    if (tid < 16){
        int ff = tid >> 2, lp = tid & 3;
        H2 a, b;
        a.h[0] = (_Float16)phr[(2*lp)*FF + f0 + ff];
        a.h[1] = (_Float16)phr[(2*lp+1)*FF + f0 + ff];
        b.h[0] = (_Float16)(-phim[(2*lp)*FF + f0 + ff]);
        b.h[1] = (_Float16)(-phim[(2*lp+1)*FF + f0 + ff]);
        phi2[0][ff][lp] = a.u;
        phi2[1][ff][lp] = b.u;
    }

    // staging lane mapping (same every kc): lane loads 4 f half2 = uint4
    int sbb = tid & 15;
    int sdd = tid >> 4;      // 0..31
    int sL = sbb + 16*(sdd >> 3), sj = sdd & 7;

    f32x4 accre[2], accim[2];
    #pragma unroll
    for (int i = 0; i < 2; ++i){
        accre[i] = (f32x4){0.f,0.f,0.f,0.f};
        accim[i] = (f32x4){0.f,0.f,0.f,0.f};
    }

    // prologue: stage kc=0 into buf 0
    {
        const uint4* src = (const uint4*)(XfH + ((size_t)(sbb*DD + sdd)*FFP + f0));
        uint4 v0 = src[0];
        unsigned int vv[4] = {v0.x, v0.y, v0.z, v0.w};
        #pragma unroll
        for (int ff = 0; ff < 4; ++ff){
            int A = ff*2048 + sL*32 + sj*4;
            int sw = (((A >> 7) & 3) << 5) | (((A >> 8) & 1) << 4);
            *(unsigned int*)((char*)Apairs[0] + (A ^ sw)) = vv[ff];
        }
    }
    __syncthreads();

    for (int kc = 0; kc < 8; ++kc){
        // theta: [lp][d][h], d = kc*32 + kp*8 + j (scalar, lane-coalesced)
        unsigned int th_pk[4][8];
        #pragma unroll
        for (int lp = 0; lp < 4; ++lp)
            #pragma unroll
            for (int j = 0; j < 8; ++j)
                th_pk[lp][j] = th16[((size_t)lp*DD + kc*32 + kp*8 + j)*DD + h];

        // stage next kc into the other buffer
        if (kc < 7){
            const uint4* src = (const uint4*)(XfH + ((size_t)(sbb*DD + (kc+1)*32 + sdd)*FFP + f0));
            uint4 v0 = src[0];
            unsigned int vv[4] = {v0.x, v0.y, v0.z, v0.w};
            #pragma unroll
            for (int ff = 0; ff < 4; ++ff){
                int A = ff*2048 + sL*32 + sj*4;
                int sw = (((A >> 7) & 3) << 5) | (((A >> 8) & 1) << 4);
                *(unsigned int*)((char*)Apairs[(kc+1)&1] + (A ^ sw)) = vv[ff];
            }
        }
        // compute kc from buf[kc&1]
        const char* bufc = (const char*)Apairs[kc & 1];
        #pragma unroll
        for (int ffl = 0; ffl < 2; ++ffl){
            int ff = fh*2 + ffl;
            unsigned int pr2[4], pi2[4];
            #pragma unroll
            for (int lp = 0; lp < 4; ++lp){
                pr2[lp] = phi2[0][ff][lp];
                pi2[lp] = phi2[1][ff][lp];
            }
            int Ab = ff*2048 + lane*32;
            int sw = (((Ab >> 7) & 3) << 5) | (((Ab >> 8) & 1) << 4);
            Ab ^= sw;
            uint4 lo = *(const uint4*)(bufc + Ab);
            uint4 hi = *(const uint4*)(bufc + (Ab ^ 16));
            unsigned int dw[8] = {lo.x, lo.y, lo.z, lo.w, hi.x, hi.y, hi.z, hi.w};
            H8 Are, Aim, Anim;
            #pragma unroll
            for (int k = 0; k < 4; ++k){
                Are.u[k]  = __builtin_amdgcn_perm(dw[2*k+1], dw[2*k], 0x05040100u);
                Aim.u[k]  = __builtin_amdgcn_perm(dw[2*k+1], dw[2*k], 0x07060302u);
                Anim.u[k] = Aim.u[k] ^ 0x80008000u;
            }
            float wre[8], wim[8];
            #pragma unroll
            for (int j = 0; j < 8; ++j){
                float re = 0.f, im = 0.f;
                #pragma unroll
                for (int lp = 0; lp < 4; ++lp){
                    re = fdot2_acc(th_pk[lp][j], pr2[lp], re);
                    im = fdot2_acc(th_pk[lp][j], pi2[lp], im);
                }
                wre[j] = re; wim[j] = im;
            }
            H8 Bre, Bim;
            #pragma unroll
            for (int j = 0; j < 8; ++j){
                Bre.h8[j] = (_Float16)wre[j];
                Bim.h8[j] = (_Float16)wim[j];
            }
            accre[ffl] = __builtin_amdgcn_mfma_f32_16x16x32_f16(Are.h8,  Bre.h8, accre[ffl], 0, 0, 0);
            accre[ffl] = __builtin_amdgcn_mfma_f32_16x16x32_f16(Anim.h8, Bim.h8, accre[ffl], 0, 0, 0);
            accim[ffl] = __builtin_amdgcn_mfma_f32_16x16x32_f16(Are.h8,  Bim.h8, accim[ffl], 0, 0, 0);
            accim[ffl] = __builtin_amdgcn_mfma_f32_16x16x32_f16(Aim.h8,  Bre.h8, accim[ffl], 0, 0, 0);
        }
        if (kc < 7) __syncthreads();
    }
    // store: f32; lane owns 16B (2 f) at f0 + fh*2
    #pragma unroll
    for (int r = 0; r < 4; ++r){
        int bb = kp*4 + r;
        PK2 pk;
        #pragma unroll
        for (int ffl = 0; ffl < 2; ++ffl)
            pk.f2[ffl] = make_float2(accre[ffl][r], accim[ffl][r]);
        *(uint4*)(Sf0 + ((size_t)(bb*DD) + h)*FFS + f0 + fh*2) = pk.q;
    }
}

// ---------------- Nyquist bin f=1024 (theta [lp][d][h]) -----------------------------
__global__ __launch_bounds__(256) void nyq_kernel(const unsigned int* __restrict__ XfH,
    const unsigned int* __restrict__ th16,
    const float* __restrict__ phr, const float* __restrict__ phim,
    float2* __restrict__ Sf0){
    __shared__ float2 red[256];
    int tid = threadIdx.x;
    int hb = blockIdx.x, b = blockIdx.y;
    int h = hb*16 + (tid & 15);
    int dp = tid >> 4;
    float pr[KK], pi[KK];
    #pragma unroll
    for (int l = 0; l < KK; ++l){ pr[l] = phr[l*FF + 1024]; pi[l] = -phim[l*FF + 1024]; }
    float2 acc = make_float2(0.f, 0.f);
    for (int j = 0; j < 16; ++j){
        int d = dp*16 + j;
        float wre = 0.f, wim = 0.f;
        #pragma unroll
        for (int lp = 0; lp < 4; ++lp){
            H2 t; t.u = th16[((size_t)lp*DD + d)*DD + h];
            float t0 = (float)t.h[0], t1 = (float)t.h[1];
            wre = fmaf(t0, pr[2*lp], fmaf(t1, pr[2*lp+1], wre));
            wim = fmaf(t0, pi[2*lp], fmaf(t1, pi[2*lp+1], wim));
        }
        H2 u; u.u = XfH[(size_t)(b*DD + d)*FFP + 1024];
        float2 x = make_float2((float)u.h[0], (float)u.h[1]);
        acc.x = fmaf(x.x, wre, fmaf(-x.y, wim, acc.x));
        acc.y = fmaf(x.x, wim, fmaf( x.y, wre, acc.y));
    }
    red[tid] = acc;
    __syncthreads();
    if (tid < 16){
        float2 s = make_float2(0.f, 0.f);
        #pragma unroll
        for (int k = 0; k < 16; ++k){ s.x += red[tid + k*16].x; s.y += red[tid + k*16].y; }
        Sf0[((size_t)b*DD + hb*16 + tid)*FFS + 1024] = s;
    }
}

// ---------------- GLU via MFMA + residual + fused LN/head ---------------------------
// MODE 0: h += GLU (f32), z = LN(h) written as f16 via outp
// MODE 1: y = head(h + GLU) written as f32 via outp
template<int MODE>
__global__ __launch_bounds__(256, 2) void glu_mfma_kernel(
    const uint4* __restrict__ Sfrag,   // [b][kc][tb][L] 16B-fragments
    const uint4* __restrict__ WfL,     // layer base: [vg][ot][kc][L] 16B
    const float* __restrict__ bv, const float* __restrict__ bg,
    float* __restrict__ h, float* __restrict__ outp,
    const float* __restrict__ aux1, const float* __restrict__ aux2){
    __shared__ float sb[1024];
    __shared__ float red[2][4][4][16];
    __shared__ float stat[2][4][16];
    int tid = threadIdx.x;
    int w = tid >> 6, lane = tid & 63;
    int tl = lane & 15, lq = lane >> 4;
    int b = blockIdx.y, tb4 = blockIdx.x;

    sb[tid] = bv[tid];
    sb[256 + tid] = bg[tid];
    sb[512 + tid] = aux1[tid];
    if (MODE == 0) sb[768 + tid] = aux2[tid];
    __syncthreads();

    f32x4 aV[4][4], aG[4][4];
    #pragma unroll
    for (int mt = 0; mt < 4; ++mt)
        #pragma unroll
        for (int nt = 0; nt < 4; ++nt){
            aV[mt][nt] = (f32x4){0.f,0.f,0.f,0.f};
            aG[mt][nt] = (f32x4){0.f,0.f,0.f,0.f};
        }

    for (int kc = 0; kc < 8; ++kc){
        H8 Bf[4];
        #pragma unroll
        for (int nt = 0; nt < 4; ++nt)
            Bf[nt].q = Sfrag[((size_t)(b*8 + kc)*128 + tb4*4 + nt)*64 + lane];
        H8 Av[4], Ag[4];
        #pragma unroll
        for (int mt = 0; mt < 4; ++mt){
            int ot = w*4 + mt;
            Av[mt].q = WfL[((size_t)(ot)*8 + kc)*64 + lane];
            Ag[mt].q = WfL[((size_t)(16 + ot)*8 + kc)*64 + lane];
        }
        #pragma unroll
        for (int mt = 0; mt < 4; ++mt)
            #pragma unroll
            for (int nt = 0; nt < 4; ++nt){
                aV[mt][nt] = __builtin_amdgcn_mfma_f32_16x16x32_f16(Av[mt].h8, Bf[nt].h8, aV[mt][nt], 0, 0, 0);
                aG[mt][nt] = __builtin_amdgcn_mfma_f32_16x16x32_f16(Ag[mt].h8, Bf[nt].h8, aG[mt][nt], 0, 0, 0);
            }
    }

    #pragma unroll
    for (int mt = 0; mt < 4; ++mt){
        #pragma unroll
        for (int r = 0; r < 4; ++r){
            int o = w*64 + mt*16 + lq*4 + r;
            float bvv = sb[o], bgv = sb[256 + o];
            float* hp = h + ((size_t)(b*DD + o))*LL + tb4*64 + tl;
            #pragma unroll
            for (int nt = 0; nt < 4; ++nt){
                float v = aV[mt][nt][r] + bvv;
                float g = aG[mt][nt][r] + bgv;
                g = 1.0f/(1.0f + __expf(-g));
                float cur = hp[nt*16] + v*g;
                if (MODE == 0) hp[nt*16] = cur;
                aV[mt][nt][r] = cur;
            }
        }
    }

    float s[4], ss[4];
    #pragma unroll
    for (int nt = 0; nt < 4; ++nt){ s[nt] = 0.f; ss[nt] = 0.f; }
    #pragma unroll
    for (int mt = 0; mt < 4; ++mt)
        #pragma unroll
        for (int r = 0; r < 4; ++r){
            int o = w*64 + mt*16 + lq*4 + r;
            float wo = (MODE == 0) ? 1.0f : sb[512 + o];
            #pragma unroll
            for (int nt = 0; nt < 4; ++nt){
                float cur = aV[mt][nt][r];
                if (MODE == 0){ s[nt] += cur; ss[nt] = fmaf(cur, cur, ss[nt]); }
                else { s[nt] = fmaf(wo, cur, s[nt]); }
            }
        }
    #pragma unroll
    for (int nt = 0; nt < 4; ++nt){
        s[nt] += __shfl_xor(s[nt], 16); s[nt] += __shfl_xor(s[nt], 32);
        if (MODE == 0){ ss[nt] += __shfl_xor(ss[nt], 16); ss[nt] += __shfl_xor(ss[nt], 32); }
    }
    if (lq == 0){
        #pragma unroll
        for (int nt = 0; nt < 4; ++nt){
            red[0][w][nt][tl] = s[nt];
            if (MODE == 0) red[1][w][nt][tl] = ss[nt];
        }
    }
    __syncthreads();
    if (MODE == 0){
        if (tid < 64){
            int nt = tid >> 4, t2 = tid & 15;
            float S1 = red[0][0][nt][t2] + red[0][1][nt][t2] + red[0][2][nt][t2] + red[0][3][nt][t2];
            float S2 = red[1][0][nt][t2] + red[1][1][nt][t2] + red[1][2][nt][t2] + red[1][3][nt][t2];
            float mu = S1*(1.0f/DD);
            float var = S2*(1.0f/DD) - mu*mu;
            stat[0][nt][t2] = mu;
            stat[1][nt][t2] = rsqrtf(var + 1e-5f);
        }
        __syncthreads();
        #pragma unroll
        for (int mt = 0; mt < 4; ++mt){
            #pragma unroll
            for (int r = 0; r < 4; ++r){
                int o = w*64 + mt*16 + lq*4 + r;
                float gam = sb[512 + o], bet = sb[768 + o];
                _Float16* zp = (_Float16*)outp + ((size_t)(b*DD + o))*LL + tb4*64 + tl;
                #pragma unroll
                for (int nt = 0; nt < 4; ++nt){
                    float zv = (aV[mt][nt][r] - stat[0][nt][tl])*stat[1][nt][tl]*gam + bet;
                    zp[nt*16] = (_Float16)zv;
                }
            }
        }
    } else {
        if (tid < 64){
            int nt = tid >> 4, t2 = tid & 15;
            float S1 = red[0][0][nt][t2] + red[0][1][nt][t2] + red[0][2][nt][t2] + red[0][3][nt][t2];
            outp[(size_t)b*LL + tb4*64 + tid] = S1 + aux2[0];
        }
    }
}

extern "C" void kernel_launch(void* const* d_in, const int* in_sizes, int n_in,
                              void* d_out, int out_size, void* d_ws, size_t ws_size,
                              hipStream_t stream){
    (void)in_sizes; (void)n_in; (void)out_size; (void)ws_size;
    const float* x      = (const float*)d_in[0];
    const float* lift_w = (const float*)d_in[1];
    const float* lift_b = (const float*)d_in[2];
    const float* theta  = (const float*)d_in[3];
    const float* ln_g   = (const float*)d_in[4];
    const float* ln_b   = (const float*)d_in[5];
    const float* gvw    = (const float*)d_in[6];
    const float* gvb    = (const float*)d_in[7];
    const float* ggw    = (const float*)d_in[8];
    const float* ggb    = (const float*)d_in[9];
    const float* hw     = (const float*)d_in[10];
    const float* hb     = (const float*)d_in[11];
    const float* phr    = (const float*)d_in[12];
    const float* phim   = (const float*)d_in[13];
    float* out = (float*)d_out;

    char* ws = (char*)d_ws;
    size_t off = 0;
    float2* tw  = (float2*)(ws + off); off += (size_t)(LL/2)*sizeof(float2);
    _Float16* Wf = (_Float16*)(ws + off); off += (size_t)NDEPTH*2*DD*DD*2;
    unsigned int* th16 = (unsigned int*)(ws + off); off += (size_t)NDEPTH*4*DD*DD*4;
    off = (off + 255) & ~(size_t)255;
    float*  h   = (float*)(ws + off);  off += (size_t)NB*DD*LL*4;
    _Float16* zh = (_Float16*)(ws + off); off += (size_t)NB*DD*LL*2;
    unsigned int* XfH = (unsigned int*)(ws + off); off += (size_t)NB*DD*FFP*4;
    unsigned int* Sfrag = XfH;   // aliased: XfH dead after nyq; Sfrag dead after glu
    off = (off + 255) & ~(size_t)255;
    float2* Sf0 = (float2*)(ws + off); off += (size_t)NB*DD*FFS*8;

    twiddle_kernel<<<4, 256, 0, stream>>>(tw);
    conv_w_kernel<<<(NDEPTH*2*DD*DD)/256, 256, 0, stream>>>(gvw, ggw, Wf);
    transpose_theta16_kernel<<<dim3(8,8,NDEPTH*4), 256, 0, stream>>>(theta, th16);
    lift_ln_kernel<<<dim3(LL/64, NB), 256, 0, stream>>>(x, lift_w, lift_b, ln_g, ln_b, h, zh);

    for (int layer = 0; layer < NDEPTH; ++layer){
        const unsigned int* thL = th16 + (size_t)layer*4*DD*DD;
        const uint4* WfL = (const uint4*)(Wf + (size_t)layer*2*DD*DD);
        fft_fwd_pair_kernel<<<NB*DD/2, 256, 0, stream>>>((const unsigned int*)zh, XfH, tw);
        spectral12_kernel<<<dim3(256,4), 512, 0, stream>>>(XfH, thL, phr, phim, Sf0);
        nyq_kernel<<<dim3(16,16), 256, 0, stream>>>(XfH, thL, phr, phim, Sf0);
        fft_inv_pair_kernel<<<NB*DD/2, 256, 0, stream>>>(Sf0, Sfrag, tw);
        if (layer < NDEPTH-1){
            glu_mfma_kernel<0><<<dim3(LL/64, NB), 256, 0, stream>>>(
                (const uint4*)Sfrag, WfL,
                gvb + layer*DD, ggb + layer*DD, h, (float*)zh,
                ln_g + (layer+1)*DD, ln_b + (layer+1)*DD);
        } else {
            glu_mfma_kernel<1><<<dim3(LL/64, NB), 256, 0, stream>>>(
                (const uint4*)Sfrag, WfL,
                gvb + layer*DD, ggb + layer*DD, h, out, hw, hb);
        }
    }
}

// Round 17
// 524.359 us; speedup vs baseline: 2.0936x; 2.0936x over previous
//
#include <hip/hip_runtime.h>
#include <math.h>

#define NB 16      // batch
#define CIN 3
#define LL 2048
#define DD 256
#define KK 8
#define NDEPTH 4
#define FF 1025
#define FFP 1032   // padded F stride for half2 Xf (u32 units)
#define FFS 1032   // padded F stride for f32 Sf (float2 units), line-aligned rows
#define LOGL 11

typedef _Float16 half8 __attribute__((ext_vector_type(8)));
typedef _Float16 half2v __attribute__((ext_vector_type(2)));
typedef float f32x4 __attribute__((ext_vector_type(4)));

union H8 { half8 h8; unsigned int u[4]; uint4 q; };
union H2 { _Float16 h[2]; unsigned int u; half2v v; };
union PK4 { float2 f2[4]; uint4 q[2]; };

#if defined(__has_builtin)
#if __has_builtin(__builtin_amdgcn_fdot2)
#define HAS_FDOT2 1
#endif
#endif

__device__ inline float fdot2_acc(unsigned int a, unsigned int b, float c){
    H2 ua, ub; ua.u = a; ub.u = b;
#ifdef HAS_FDOT2
    return __builtin_amdgcn_fdot2(ua.v, ub.v, c, false);
#else
    return c + (float)ua.h[0]*(float)ub.h[0] + (float)ua.h[1]*(float)ub.h[1];
#endif
}

__device__ inline float2 cmul(const float2 a, const float2 b){
    return make_float2(a.x*b.x - a.y*b.y, a.x*b.y + a.y*b.x);
}
__device__ inline float2 cadd(const float2 a, const float2 b){ return make_float2(a.x+b.x, a.y+b.y); }
__device__ inline float2 csub(const float2 a, const float2 b){ return make_float2(a.x-b.x, a.y-b.y); }

// radix-8 triple (stages s, s+1, s+2), one 8-group per thread (g in [0,256))
template<bool CONJ>
__device__ inline void r8_stage(float2* a, const float2* __restrict__ tw, int g, int s){
    const int hs = 1 << s;
    int pos = g & (hs-1);
    int grp = g >> s;
    int q = (grp << (s+3)) + pos;
    float2 ws = tw[pos << (LOGL-1-s)];
    float2 w1 = tw[pos << (LOGL-2-s)];
    float2 w2 = tw[(pos+hs) << (LOGL-2-s)];
    float2 v0 = tw[pos << (LOGL-3-s)];
    float2 v1 = tw[(pos+hs) << (LOGL-3-s)];
    float2 v2 = tw[(pos+2*hs) << (LOGL-3-s)];
    float2 v3 = tw[(pos+3*hs) << (LOGL-3-s)];
    if (CONJ){ ws.y=-ws.y; w1.y=-w1.y; w2.y=-w2.y; v0.y=-v0.y; v1.y=-v1.y; v2.y=-v2.y; v3.y=-v3.y; }
    float2 A0=a[q],      A1=a[q+hs],   A2=a[q+2*hs], A3=a[q+3*hs],
           A4=a[q+4*hs], A5=a[q+5*hs], A6=a[q+6*hs], A7=a[q+7*hs];
    float2 t;
    t=cmul(ws,A1); float2 b0=cadd(A0,t), b1=csub(A0,t);
    t=cmul(ws,A3); float2 b2=cadd(A2,t), b3=csub(A2,t);
    t=cmul(ws,A5); float2 b4=cadd(A4,t), b5=csub(A4,t);
    t=cmul(ws,A7); float2 b6=cadd(A6,t), b7=csub(A6,t);
    t=cmul(w1,b2); float2 c0=cadd(b0,t), c2=csub(b0,t);
    t=cmul(w2,b3); float2 c1=cadd(b1,t), c3=csub(b1,t);
    t=cmul(w1,b6); float2 c4=cadd(b4,t), c6=csub(b4,t);
    t=cmul(w2,b7); float2 c5=cadd(b5,t), c7=csub(b5,t);
    t=cmul(v0,c4); a[q]      =cadd(c0,t); a[q+4*hs]=csub(c0,t);
    t=cmul(v1,c5); a[q+hs]   =cadd(c1,t); a[q+5*hs]=csub(c1,t);
    t=cmul(v2,c6); a[q+2*hs] =cadd(c2,t); a[q+6*hs]=csub(c2,t);
    t=cmul(v3,c7); a[q+3*hs] =cadd(c3,t); a[q+7*hs]=csub(c3,t);
}

// final radix-4 pair (stages 9,10), one 4-group per call (g in [0,512))
template<bool CONJ>
__device__ inline void r4_final(float2* a, const float2* __restrict__ tw, int g){
    int pos = g;
    float2 ws = tw[pos << 1];
    float2 w1 = tw[pos];
    float2 w2 = tw[pos + 512];
    if (CONJ){ ws.y=-ws.y; w1.y=-w1.y; w2.y=-w2.y; }
    float2 a0 = a[pos], a1 = a[pos+512], a2 = a[pos+1024], a3 = a[pos+1536];
    float2 t1 = cmul(ws, a1), t3 = cmul(ws, a3);
    float2 x0 = cadd(a0,t1), x1 = csub(a0,t1);
    float2 x2 = cadd(a2,t3), x3 = csub(a2,t3);
    float2 u1 = cmul(w1, x2), u2 = cmul(w2, x3);
    a[pos]      = cadd(x0,u1);
    a[pos+1024] = csub(x0,u1);
    a[pos+512]  = cadd(x1,u2);
    a[pos+1536] = csub(x1,u2);
}

// ---------------- twiddle table ----------------------------------------------------
__global__ void twiddle_kernel(float2* __restrict__ tw){
    int j = blockIdx.x*blockDim.x + threadIdx.x;
    if (j < LL/2){
        double ang = -2.0*3.14159265358979323846*(double)j/(double)LL;
        tw[j] = make_float2((float)cos(ang), (float)sin(ang));
    }
}

// ---------------- convert GLU weights to f16 A-fragment layout ----------------------
__global__ void conv_w_kernel(const float* __restrict__ wv, const float* __restrict__ wg,
                              _Float16* __restrict__ Wf){
    int idx = blockIdx.x*256 + threadIdx.x;   // NDEPTH*2*DD*DD
    int layer = idx >> 17;
    int vg = (idx >> 16) & 1;
    int rem = idx & 65535;
    int o = rem >> 8, d = rem & 255;
    const float* src = (vg ? wg : wv) + ((size_t)layer << 16);
    float val = src[(o << 8) + d];
    size_t dst = ((((size_t)(layer*2+vg)*16 + (o>>4))*8 + (d>>5))*64
                  + (o&15) + 16*((d>>3)&3))*8 + (d&7);
    Wf[dst] = (_Float16)val;
}

// ---------------- theta -> f16 l-pair-packed, transposed: [layer][lp][d][h] half2 ---
__global__ void transpose_theta16_kernel(const float* __restrict__ in,
                                         unsigned int* __restrict__ out){
    __shared__ float tile[2][32][33];
    int m = blockIdx.z;                  // layer*4 + lp
    int layer = m >> 2, lp = m & 3;
    int d0 = blockIdx.x*32, h0 = blockIdx.y*32;
    int tx = threadIdx.x & 31, ty = threadIdx.x >> 5;   // 32 x 8
    const float* src0 = in + ((size_t)layer*KK + 2*lp)*DD*DD;
    const float* src1 = src0 + (size_t)DD*DD;
    #pragma unroll
    for (int i = 0; i < 4; ++i){
        tile[0][ty + i*8][tx] = src0[(size_t)(h0 + ty + i*8)*DD + d0 + tx];
        tile[1][ty + i*8][tx] = src1[(size_t)(h0 + ty + i*8)*DD + d0 + tx];
    }
    __syncthreads();
    #pragma unroll
    for (int i = 0; i < 4; ++i){
        H2 p;
        p.h[0] = (_Float16)tile[0][tx][ty + i*8];
        p.h[1] = (_Float16)tile[1][tx][ty + i*8];
        out[((size_t)m*DD + d0 + ty + i*8)*DD + h0 + tx] = p.u;
    }
}

// ---------------- lift + LayerNorm(layer 0): h f32, z f16 ---------------------------
__global__ __launch_bounds__(256) void lift_ln_kernel(const float* __restrict__ x,
        const float* __restrict__ lw, const float* __restrict__ lb,
        const float* __restrict__ gamma, const float* __restrict__ beta,
        float* __restrict__ h, _Float16* __restrict__ z){
    __shared__ float red[2][4][64];
    __shared__ float stat[2][64];
    __shared__ float gb[512];
    int tid = threadIdx.x;
    int t = tid & 63, dg = tid >> 6;
    int b = blockIdx.y;
    int tg = blockIdx.x*64 + t;
    gb[tid] = gamma[tid];
    gb[256 + tid] = beta[tid];
    const float* xb = x + (size_t)b*CIN*LL;
    float x0 = xb[tg], x1 = xb[LL + tg], x2 = xb[2*LL + tg];
    float coord = (float)tg * (1.0f/(LL-1));
    float hv[64];
    float s = 0.f, ss = 0.f;
    float* hp = h + (size_t)b*DD*LL + tg;
    #pragma unroll
    for (int j = 0; j < 64; ++j){
        int d = dg*64 + j;
        float4 w = *(const float4*)&lw[d*4];
        float v = lb[d];
        v = fmaf(w.x, x0, v); v = fmaf(w.y, x1, v);
        v = fmaf(w.z, x2, v); v = fmaf(w.w, coord, v);
        hv[j] = v;
        s += v; ss = fmaf(v, v, ss);
        hp[(size_t)d*LL] = v;
    }
    red[0][dg][t] = s; red[1][dg][t] = ss;
    __syncthreads();
    if (tid < 64){
        float S1 = red[0][0][tid] + red[0][1][tid] + red[0][2][tid] + red[0][3][tid];
        float S2 = red[1][0][tid] + red[1][1][tid] + red[1][2][tid] + red[1][3][tid];
        float mu = S1*(1.0f/DD);
        float var = S2*(1.0f/DD) - mu*mu;
        stat[0][tid] = mu;
        stat[1][tid] = rsqrtf(var + 1e-5f);
    }
    __syncthreads();
    float mu = stat[0][t], rs = stat[1][t];
    _Float16* zp = z + (size_t)b*DD*LL + tg;
    #pragma unroll
    for (int j = 0; j < 64; ++j){
        int d = dg*64 + j;
        zp[(size_t)d*LL] = (_Float16)((hv[j] - mu)*rs*gb[d] + gb[256 + d]);
    }
}

// ---------------- forward FFT (radix-8), reads f16 z, 2 real channels packed --------
__global__ __launch_bounds__(256) void fft_fwd_pair_kernel(const unsigned int* __restrict__ zh,
                                                           unsigned int* __restrict__ XfH,
                                                           const float2* __restrict__ tw){
    __shared__ float2 a[LL];
    int blk = blockIdx.x;
    const unsigned int* s0 = zh + (size_t)(blk*2)*(LL/2);
    const unsigned int* s1 = s0 + (LL/2);
    int tid = threadIdx.x;
    #pragma unroll
    for (int i = 0; i < 4; ++i){
        int tp = tid + i*256;           // t-pair index 0..1023
        H2 u0, u1;
        u0.u = s0[tp];
        u1.u = s1[tp];
        int t0 = 2*tp, t1 = 2*tp + 1;
        int r0 = __brev((unsigned)t0) >> (32-LOGL);
        int r1 = __brev((unsigned)t1) >> (32-LOGL);
        a[r0] = make_float2((float)u0.h[0], (float)u1.h[0]);
        a[r1] = make_float2((float)u0.h[1], (float)u1.h[1]);
    }
    __syncthreads();
    r8_stage<false>(a, tw, tid, 0);  __syncthreads();
    r8_stage<false>(a, tw, tid, 3);  __syncthreads();
    r8_stage<false>(a, tw, tid, 6);  __syncthreads();
    r4_final<false>(a, tw, tid);
    r4_final<false>(a, tw, tid + 256);
    __syncthreads();
    unsigned int* dst0 = XfH + (size_t)(blk*2)*FFP;
    unsigned int* dst1 = dst0 + FFP;
    #pragma unroll
    for (int i = 0; i < 5; ++i){
        int f = tid + i*256;
        if (f <= 1024){
            int m = (LL - f) & (LL-1);
            float2 A = a[f], B = a[m];
            H2 p0, p1;
            p0.h[0] = (_Float16)(0.5f*(A.x + B.x));
            p0.h[1] = (_Float16)(0.5f*(A.y - B.y));
            p1.h[0] = (_Float16)(0.5f*(A.y + B.y));
            p1.h[1] = (_Float16)(0.5f*(B.x - A.x));
            dst0[f] = p0.u;
            dst1[f] = p1.u;
        }
    }
    if (tid < 7){
        dst0[1025 + tid] = 0u;
        dst1[1025 + tid] = 0u;
    }
}

// ---------------- inverse FFT (radix-8), reads f32 Sf, writes Sfrag -----------------
__global__ __launch_bounds__(256) void fft_inv_pair_kernel(const float2* __restrict__ Sf0,
                                                           unsigned int* __restrict__ Sfrag,
                                                           const float2* __restrict__ tw){
    __shared__ float2 a[LL];
    int blk = blockIdx.x;
    const float2* src0 = Sf0 + (size_t)(blk*2)*FFS;
    const float2* src1 = src0 + FFS;
    int tid = threadIdx.x;
    #pragma unroll
    for (int i = 0; i < LL/256; ++i){
        int idx = tid + i*256;
        float2 Y;
        if (idx <= 1024){
            float2 s0 = src0[idx], s1 = src1[idx];
            Y = make_float2(s0.x - s1.y, s0.y + s1.x);
        } else {
            int m = LL - idx;
            float2 s0 = src0[m], s1 = src1[m];
            Y = make_float2(s0.x + s1.y, s1.x - s0.y);
        }
        int rev = __brev((unsigned)idx) >> (32-LOGL);
        a[rev] = Y;
    }
    __syncthreads();
    r8_stage<true>(a, tw, tid, 0);  __syncthreads();
    r8_stage<true>(a, tw, tid, 3);  __syncthreads();
    r8_stage<true>(a, tw, tid, 6);  __syncthreads();
    r4_final<true>(a, tw, tid);
    r4_final<true>(a, tw, tid + 256);
    __syncthreads();
    int b = blk >> 7, dl = (blk & 127)*2;
    int kc = dl >> 5, lq4 = (dl >> 3) & 3, jh = (dl & 7) >> 1;
    unsigned int* dst = Sfrag + ((size_t)(b*8 + kc)*128)*64*4;
    const float sc = 1.0f/(float)LL;
    #pragma unroll
    for (int i = 0; i < LL/256; ++i){
        int t = tid + i*256;
        float2 v = a[t];
        H2 p;
        p.h[0] = (_Float16)(v.x*sc);
        p.h[1] = (_Float16)(v.y*sc);
        dst[(((t>>4)*64) + (t&15) + 16*lq4)*4 + jh] = p.u;
    }
}

// ---------------- spectral v9 (r13 best): full 32-bank LDS swizzle ------------------
// 8 waves = (hc 0-3) x (ffhalf 0-1); per wave 4 ff x 16 h; grid (128, 4).
__global__ __launch_bounds__(512, 4) void spectral7_kernel(
    const unsigned int* __restrict__ XfH,   // [b][d][FFP] half2 (re,im)
    const unsigned int* __restrict__ th16,  // [4][d][h] this layer, l-pair half2
    const float* __restrict__ phr, const float* __restrict__ phim,
    float2* __restrict__ Sf0){
    __shared__ unsigned int Apairs[8*64*8];   // 16 KB, swizzled fragment layout
    __shared__ unsigned int phi2[2][8][4];    // [pr/pi][ff][lp] f16 l-pairs
    int tid = threadIdx.x;
    int w = tid >> 6, lane = tid & 63;
    int hc = w & 3, fh = w >> 2;
    int n = lane & 15, kp = lane >> 4;
    int f0 = blockIdx.x * 8;
    int h0 = blockIdx.y * 64;
    int h = h0 + hc*16 + n;

    if (tid < 32){
        int ff = tid >> 2, lp = tid & 3;
        H2 a, b;
        a.h[0] = (_Float16)phr[(2*lp)*FF + f0 + ff];
        a.h[1] = (_Float16)phr[(2*lp+1)*FF + f0 + ff];
        b.h[0] = (_Float16)(-phim[(2*lp)*FF + f0 + ff]);
        b.h[1] = (_Float16)(-phim[(2*lp+1)*FF + f0 + ff]);
        phi2[0][ff][lp] = a.u;
        phi2[1][ff][lp] = b.u;
    }

    f32x4 accre[4], accim[4];
    #pragma unroll
    for (int i = 0; i < 4; ++i){
        accre[i] = (f32x4){0.f,0.f,0.f,0.f};
        accim[i] = (f32x4){0.f,0.f,0.f,0.f};
    }

    for (int kc = 0; kc < 8; ++kc){
        unsigned int th_pk[4][8];
        #pragma unroll
        for (int lp = 0; lp < 4; ++lp)
            #pragma unroll
            for (int j = 0; j < 8; ++j)
                th_pk[lp][j] = th16[((size_t)lp*DD + kc*32 + kp*8 + j)*DD + h];

        __syncthreads();
        {
            int bb = tid & 15;
            int dd = tid >> 4;      // 0..31
            const uint4* src = (const uint4*)(XfH + ((size_t)(bb*DD + kc*32 + dd)*FFP + f0));
            uint4 v0 = src[0], v1 = src[1];
            int L = bb + 16*(dd >> 3), j = dd & 7;
            unsigned int vv[8] = {v0.x, v0.y, v0.z, v0.w, v1.x, v1.y, v1.z, v1.w};
            #pragma unroll
            for (int ff = 0; ff < 8; ++ff){
                int A = ff*2048 + L*32 + j*4;
                int sw = (((A >> 7) & 3) << 5) | (((A >> 8) & 1) << 4);
                *(unsigned int*)((char*)Apairs + (A ^ sw)) = vv[ff];
            }
        }
        __syncthreads();

        #pragma unroll
        for (int ffl = 0; ffl < 4; ++ffl){
            int ff = fh*4 + ffl;
            unsigned int pr2[4], pi2[4];
            #pragma unroll
            for (int lp = 0; lp < 4; ++lp){
                pr2[lp] = phi2[0][ff][lp];
                pi2[lp] = phi2[1][ff][lp];
            }
            int Ab = ff*2048 + lane*32;
            int sw = (((Ab >> 7) & 3) << 5) | (((Ab >> 8) & 1) << 4);
            Ab ^= sw;
            uint4 lo = *(const uint4*)((const char*)Apairs + Ab);
            uint4 hi = *(const uint4*)((const char*)Apairs + (Ab ^ 16));
            unsigned int dw[8] = {lo.x, lo.y, lo.z, lo.w, hi.x, hi.y, hi.z, hi.w};
            H8 Are, Aim, Anim;
            #pragma unroll
            for (int k = 0; k < 4; ++k){
                Are.u[k]  = __builtin_amdgcn_perm(dw[2*k+1], dw[2*k], 0x05040100u);
                Aim.u[k]  = __builtin_amdgcn_perm(dw[2*k+1], dw[2*k], 0x07060302u);
                Anim.u[k] = Aim.u[k] ^ 0x80008000u;
            }
            float wre[8], wim[8];
            #pragma unroll
            for (int j = 0; j < 8; ++j){
                float re = 0.f, im = 0.f;
                #pragma unroll
                for (int lp = 0; lp < 4; ++lp){
                    re = fdot2_acc(th_pk[lp][j], pr2[lp], re);
                    im = fdot2_acc(th_pk[lp][j], pi2[lp], im);
                }
                wre[j] = re; wim[j] = im;
            }
            H8 Bre, Bim;
            #pragma unroll
            for (int j = 0; j < 8; ++j){
                Bre.h8[j] = (_Float16)wre[j];
                Bim.h8[j] = (_Float16)wim[j];
            }
            accre[ffl] = __builtin_amdgcn_mfma_f32_16x16x32_f16(Are.h8,  Bre.h8, accre[ffl], 0, 0, 0);
            accre[ffl] = __builtin_amdgcn_mfma_f32_16x16x32_f16(Anim.h8, Bim.h8, accre[ffl], 0, 0, 0);
            accim[ffl] = __builtin_amdgcn_mfma_f32_16x16x32_f16(Are.h8,  Bim.h8, accim[ffl], 0, 0, 0);
            accim[ffl] = __builtin_amdgcn_mfma_f32_16x16x32_f16(Aim.h8,  Bre.h8, accim[ffl], 0, 0, 0);
        }
    }
    // store: f32; lane owns 32B at f0 + fh*4; sibling wave covers other 32B of line
    #pragma unroll
    for (int r = 0; r < 4; ++r){
        int bb = kp*4 + r;
        PK4 pk;
        #pragma unroll
        for (int ffl = 0; ffl < 4; ++ffl)
            pk.f2[ffl] = make_float2(accre[ffl][r], accim[ffl][r]);
        uint4* dst = (uint4*)(Sf0 + ((size_t)(bb*DD) + h)*FFS + f0 + fh*4);
        dst[0] = pk.q[0]; dst[1] = pk.q[1];
    }
}

// ---------------- Nyquist bin f=1024 (theta [lp][d][h]) -----------------------------
__global__ __launch_bounds__(256) void nyq_kernel(const unsigned int* __restrict__ XfH,
    const unsigned int* __restrict__ th16,
    const float* __restrict__ phr, const float* __restrict__ phim,
    float2* __restrict__ Sf0){
    __shared__ float2 red[256];
    int tid = threadIdx.x;
    int hb = blockIdx.x, b = blockIdx.y;
    int h = hb*16 + (tid & 15);
    int dp = tid >> 4;
    float pr[KK], pi[KK];
    #pragma unroll
    for (int l = 0; l < KK; ++l){ pr[l] = phr[l*FF + 1024]; pi[l] = -phim[l*FF + 1024]; }
    float2 acc = make_float2(0.f, 0.f);
    for (int j = 0; j < 16; ++j){
        int d = dp*16 + j;
        float wre = 0.f, wim = 0.f;
        #pragma unroll
        for (int lp = 0; lp < 4; ++lp){
            H2 t; t.u = th16[((size_t)lp*DD + d)*DD + h];
            float t0 = (float)t.h[0], t1 = (float)t.h[1];
            wre = fmaf(t0, pr[2*lp], fmaf(t1, pr[2*lp+1], wre));
            wim = fmaf(t0, pi[2*lp], fmaf(t1, pi[2*lp+1], wim));
        }
        H2 u; u.u = XfH[(size_t)(b*DD + d)*FFP + 1024];
        float2 x = make_float2((float)u.h[0], (float)u.h[1]);
        acc.x = fmaf(x.x, wre, fmaf(-x.y, wim, acc.x));
        acc.y = fmaf(x.x, wim, fmaf( x.y, wre, acc.y));
    }
    red[tid] = acc;
    __syncthreads();
    if (tid < 16){
        float2 s = make_float2(0.f, 0.f);
        #pragma unroll
        for (int k = 0; k < 16; ++k){ s.x += red[tid + k*16].x; s.y += red[tid + k*16].y; }
        Sf0[((size_t)b*DD + hb*16 + tid)*FFS + 1024] = s;
    }
}

// ---------------- GLU via MFMA + residual + fused LN/head ---------------------------
// MODE 0: h += GLU (f32), z = LN(h) written as f16 via outp
// MODE 1: y = head(h + GLU) written as f32 via outp
template<int MODE>
__global__ __launch_bounds__(256, 2) void glu_mfma_kernel(
    const uint4* __restrict__ Sfrag,   // [b][kc][tb][L] 16B-fragments
    const uint4* __restrict__ WfL,     // layer base: [vg][ot][kc][L] 16B
    const float* __restrict__ bv, const float* __restrict__ bg,
    float* __restrict__ h, float* __restrict__ outp,
    const float* __restrict__ aux1, const float* __restrict__ aux2){
    __shared__ float sb[1024];
    __shared__ float red[2][4][4][16];
    __shared__ float stat[2][4][16];
    int tid = threadIdx.x;
    int w = tid >> 6, lane = tid & 63;
    int tl = lane & 15, lq = lane >> 4;
    int b = blockIdx.y, tb4 = blockIdx.x;

    sb[tid] = bv[tid];
    sb[256 + tid] = bg[tid];
    sb[512 + tid] = aux1[tid];
    if (MODE == 0) sb[768 + tid] = aux2[tid];
    __syncthreads();

    f32x4 aV[4][4], aG[4][4];
    #pragma unroll
    for (int mt = 0; mt < 4; ++mt)
        #pragma unroll
        for (int nt = 0; nt < 4; ++nt){
            aV[mt][nt] = (f32x4){0.f,0.f,0.f,0.f};
            aG[mt][nt] = (f32x4){0.f,0.f,0.f,0.f};
        }

    for (int kc = 0; kc < 8; ++kc){
        H8 Bf[4];
        #pragma unroll
        for (int nt = 0; nt < 4; ++nt)
            Bf[nt].q = Sfrag[((size_t)(b*8 + kc)*128 + tb4*4 + nt)*64 + lane];
        H8 Av[4], Ag[4];
        #pragma unroll
        for (int mt = 0; mt < 4; ++mt){
            int ot = w*4 + mt;
            Av[mt].q = WfL[((size_t)(ot)*8 + kc)*64 + lane];
            Ag[mt].q = WfL[((size_t)(16 + ot)*8 + kc)*64 + lane];
        }
        #pragma unroll
        for (int mt = 0; mt < 4; ++mt)
            #pragma unroll
            for (int nt = 0; nt < 4; ++nt){
                aV[mt][nt] = __builtin_amdgcn_mfma_f32_16x16x32_f16(Av[mt].h8, Bf[nt].h8, aV[mt][nt], 0, 0, 0);
                aG[mt][nt] = __builtin_amdgcn_mfma_f32_16x16x32_f16(Ag[mt].h8, Bf[nt].h8, aG[mt][nt], 0, 0, 0);
            }
    }

    #pragma unroll
    for (int mt = 0; mt < 4; ++mt){
        #pragma unroll
        for (int r = 0; r < 4; ++r){
            int o = w*64 + mt*16 + lq*4 + r;
            float bvv = sb[o], bgv = sb[256 + o];
            float* hp = h + ((size_t)(b*DD + o))*LL + tb4*64 + tl;
            #pragma unroll
            for (int nt = 0; nt < 4; ++nt){
                float v = aV[mt][nt][r] + bvv;
                float g = aG[mt][nt][r] + bgv;
                g = 1.0f/(1.0f + __expf(-g));
                float cur = hp[nt*16] + v*g;
                if (MODE == 0) hp[nt*16] = cur;
                aV[mt][nt][r] = cur;
            }
        }
    }

    float s[4], ss[4];
    #pragma unroll
    for (int nt = 0; nt < 4; ++nt){ s[nt] = 0.f; ss[nt] = 0.f; }
    #pragma unroll
    for (int mt = 0; mt < 4; ++mt)
        #pragma unroll
        for (int r = 0; r < 4; ++r){
            int o = w*64 + mt*16 + lq*4 + r;
            float wo = (MODE == 0) ? 1.0f : sb[512 + o];
            #pragma unroll
            for (int nt = 0; nt < 4; ++nt){
                float cur = aV[mt][nt][r];
                if (MODE == 0){ s[nt] += cur; ss[nt] = fmaf(cur, cur, ss[nt]); }
                else { s[nt] = fmaf(wo, cur, s[nt]); }
            }
        }
    #pragma unroll
    for (int nt = 0; nt < 4; ++nt){
        s[nt] += __shfl_xor(s[nt], 16); s[nt] += __shfl_xor(s[nt], 32);
        if (MODE == 0){ ss[nt] += __shfl_xor(ss[nt], 16); ss[nt] += __shfl_xor(ss[nt], 32); }
    }
    if (lq == 0){
        #pragma unroll
        for (int nt = 0; nt < 4; ++nt){
            red[0][w][nt][tl] = s[nt];
            if (MODE == 0) red[1][w][nt][tl] = ss[nt];
        }
    }
    __syncthreads();
    if (MODE == 0){
        if (tid < 64){
            int nt = tid >> 4, t2 = tid & 15;
            float S1 = red[0][0][nt][t2] + red[0][1][nt][t2] + red[0][2][nt][t2] + red[0][3][nt][t2];
            float S2 = red[1][0][nt][t2] + red[1][1][nt][t2] + red[1][2][nt][t2] + red[1][3][nt][t2];
            float mu = S1*(1.0f/DD);
            float var = S2*(1.0f/DD) - mu*mu;
            stat[0][nt][t2] = mu;
            stat[1][nt][t2] = rsqrtf(var + 1e-5f);
        }
        __syncthreads();
        #pragma unroll
        for (int mt = 0; mt < 4; ++mt){
            #pragma unroll
            for (int r = 0; r < 4; ++r){
                int o = w*64 + mt*16 + lq*4 + r;
                float gam = sb[512 + o], bet = sb[768 + o];
                _Float16* zp = (_Float16*)outp + ((size_t)(b*DD + o))*LL + tb4*64 + tl;
                #pragma unroll
                for (int nt = 0; nt < 4; ++nt){
                    float zv = (aV[mt][nt][r] - stat[0][nt][tl])*stat[1][nt][tl]*gam + bet;
                    zp[nt*16] = (_Float16)zv;
                }
            }
        }
    } else {
        if (tid < 64){
            int nt = tid >> 4, t2 = tid & 15;
            float S1 = red[0][0][nt][t2] + red[0][1][nt][t2] + red[0][2][nt][t2] + red[0][3][nt][t2];
            outp[(size_t)b*LL + tb4*64 + tid] = S1 + aux2[0];
        }
    }
}

extern "C" void kernel_launch(void* const* d_in, const int* in_sizes, int n_in,
                              void* d_out, int out_size, void* d_ws, size_t ws_size,
                              hipStream_t stream){
    (void)in_sizes; (void)n_in; (void)out_size; (void)ws_size;
    const float* x      = (const float*)d_in[0];
    const float* lift_w = (const float*)d_in[1];
    const float* lift_b = (const float*)d_in[2];
    const float* theta  = (const float*)d_in[3];
    const float* ln_g   = (const float*)d_in[4];
    const float* ln_b   = (const float*)d_in[5];
    const float* gvw    = (const float*)d_in[6];
    const float* gvb    = (const float*)d_in[7];
    const float* ggw    = (const float*)d_in[8];
    const float* ggb    = (const float*)d_in[9];
    const float* hw     = (const float*)d_in[10];
    const float* hb     = (const float*)d_in[11];
    const float* phr    = (const float*)d_in[12];
    const float* phim   = (const float*)d_in[13];
    float* out = (float*)d_out;

    char* ws = (char*)d_ws;
    size_t off = 0;
    float2* tw  = (float2*)(ws + off); off += (size_t)(LL/2)*sizeof(float2);
    _Float16* Wf = (_Float16*)(ws + off); off += (size_t)NDEPTH*2*DD*DD*2;
    unsigned int* th16 = (unsigned int*)(ws + off); off += (size_t)NDEPTH*4*DD*DD*4;
    off = (off + 255) & ~(size_t)255;
    float*  h   = (float*)(ws + off);  off += (size_t)NB*DD*LL*4;
    _Float16* zh = (_Float16*)(ws + off); off += (size_t)NB*DD*LL*2;
    unsigned int* XfH = (unsigned int*)(ws + off); off += (size_t)NB*DD*FFP*4;
    unsigned int* Sfrag = XfH;   // aliased: XfH dead after nyq; Sfrag dead after glu
    off = (off + 255) & ~(size_t)255;
    float2* Sf0 = (float2*)(ws + off); off += (size_t)NB*DD*FFS*8;

    twiddle_kernel<<<4, 256, 0, stream>>>(tw);
    conv_w_kernel<<<(NDEPTH*2*DD*DD)/256, 256, 0, stream>>>(gvw, ggw, Wf);
    transpose_theta16_kernel<<<dim3(8,8,NDEPTH*4), 256, 0, stream>>>(theta, th16);
    lift_ln_kernel<<<dim3(LL/64, NB), 256, 0, stream>>>(x, lift_w, lift_b, ln_g, ln_b, h, zh);

    for (int layer = 0; layer < NDEPTH; ++layer){
        const unsigned int* thL = th16 + (size_t)layer*4*DD*DD;
        const uint4* WfL = (const uint4*)(Wf + (size_t)layer*2*DD*DD);
        fft_fwd_pair_kernel<<<NB*DD/2, 256, 0, stream>>>((const unsigned int*)zh, XfH, tw);
        spectral7_kernel<<<dim3(128,4), 512, 0, stream>>>(XfH, thL, phr, phim, Sf0);
        nyq_kernel<<<dim3(16,16), 256, 0, stream>>>(XfH, thL, phr, phim, Sf0);
        fft_inv_pair_kernel<<<NB*DD/2, 256, 0, stream>>>(Sf0, Sfrag, tw);
        if (layer < NDEPTH-1){
            glu_mfma_kernel<0><<<dim3(LL/64, NB), 256, 0, stream>>>(
                (const uint4*)Sfrag, WfL,
                gvb + layer*DD, ggb + layer*DD, h, (float*)zh,
                ln_g + (layer+1)*DD, ln_b + (layer+1)*DD);
        } else {
            glu_mfma_kernel<1><<<dim3(LL/64, NB), 256, 0, stream>>>(
                (const uint4*)Sfrag, WfL,
                gvb + layer*DD, ggb + layer*DD, h, out, hw, hb);
        }
    }
}